// Round 5
// baseline (359.717 us; speedup 1.0000x reference)
//
#include <hip/hip_runtime.h>
#include <stdint.h>
#include <math.h>

#define T_DIM 8192
#define D_DIM 4096
#define E_DIM 64
#define TE (T_DIM * E_DIM)  // 524288
#define GAP_MARGIN 2e-3     // > 2x provable worst-case bf16-split logit error (9.4e-4)
#define ROWS 16             // rows per block (mfma kernel)
#define NKSTEP (D_DIM / 32) // 128 MFMA k-steps
#define FIX_WAVES 8
#define FIX_COLS (D_DIM / FIX_WAVES)  // 512 cols per wave

typedef __attribute__((ext_vector_type(8))) short short8_t;  // 8 bf16 (4 VGPRs)
typedef __attribute__((ext_vector_type(4))) float f32x4;

// ============================================================================
// W bf16 hi/lo planes in fragment-linear order, filled once per call by
// w_split_kernel. idx = ks*2048 + subE*512 + q*128 + ee*8 + j where
// e = subE*16+ee, k = ks*32 + q*8 + j. The per-wave B-fragment read
// (n=lane&15 -> ee, q=lane>>4) is a fully-coalesced 1KB global_load_dwordx4
// per wave at address plane + ks*2048 + b_off — B never touches LDS.
// ============================================================================
__device__ __align__(16) short Whi_g[E_DIM * D_DIM];  // 512 KB
__device__ __align__(16) short Wlo_g[E_DIM * D_DIM];  // 512 KB

// ============================================================================
// Threefry-2x32, key = (0, 42), 20 rounds — VALIDATED (prior session r3/4/5)
// ============================================================================
__device__ __forceinline__ void threefry2x32_k42(uint32_t x0, uint32_t x1,
                                                 uint32_t& o0, uint32_t& o1) {
  const uint32_t ks0 = 0u, ks1 = 42u;
  const uint32_t ks2 = 0x1BD11BDAu ^ ks0 ^ ks1;
  x0 += ks0; x1 += ks1;
#define TF_RND(r) { x0 += x1; x1 = (x1 << (r)) | (x1 >> (32 - (r))); x1 ^= x0; }
  TF_RND(13) TF_RND(15) TF_RND(26) TF_RND(6)   x0 += ks1; x1 += ks2 + 1u;
  TF_RND(17) TF_RND(29) TF_RND(16) TF_RND(24)  x0 += ks2; x1 += ks0 + 2u;
  TF_RND(13) TF_RND(15) TF_RND(26) TF_RND(6)   x0 += ks0; x1 += ks1 + 3u;
  TF_RND(17) TF_RND(29) TF_RND(16) TF_RND(24)  x0 += ks1; x1 += ks2 + 4u;
  TF_RND(13) TF_RND(15) TF_RND(26) TF_RND(6)   x0 += ks2; x1 += ks0 + 5u;
#undef TF_RND
  o0 = x0; o1 = x1;
}

__device__ __forceinline__ uint32_t jax_random_bits32(uint32_t j) {
  uint32_t o0, o1;
  threefry2x32_k42(0u, j, o0, o1);
  return o0 ^ o1;
}

// f64 finalize per row (lane = expert) — VALIDATED, unchanged
__device__ __forceinline__ void finalize_row_f64(double logit, int e, int t,
                                                 float& mask_out, float& weight_out,
                                                 double& gap_out) {
  double m = logit;
#pragma unroll
  for (int off = 1; off < 64; off <<= 1) {
    const double om = __shfl_xor(m, off, 64);
    m = (om > m) ? om : m;
  }
  const double pe = exp(logit - m);
  double s = pe;
#pragma unroll
  for (int off = 1; off < 64; off <<= 1) s += __shfl_xor(s, off, 64);
  weight_out = (float)(pe / s);

  const int idx = t * 64 + e;
  const uint32_t bits = jax_random_bits32((uint32_t)idx);
  const float f01 = __uint_as_float((bits >> 9) | 0x3f800000u) - 1.0f;
  const float minv = 1e-6f;
  const float maxv = 0.999999f;
  float u = __fadd_rn(__fmul_rn(f01, maxv - minv), minv);
  u = fmaxf(minv, u);
  const double g = -log(-log((double)u));
  const double sel = logit + g;

  float mask = 0.0f;
  double cur = sel;
  double v8 = 0.0, v9 = 0.0;
  for (int it = 0; it < 9; ++it) {
    double v = cur;
    int vi = e;
#pragma unroll
    for (int off = 1; off < 64; off <<= 1) {
      const double ov = __shfl_xor(v, off, 64);
      const int    oi = __shfl_xor(vi, off, 64);
      if (ov > v || (ov == v && oi < vi)) { v = ov; vi = oi; }
    }
    if (it < 8) {
      if (vi == e) { mask = 1.0f; cur = -__builtin_inf(); }
      if (it == 7) v8 = v;
    } else {
      v9 = v;
    }
  }
  mask_out = mask;
  gap_out = v8 - v9;
}

// fp32 -> bf16 (RNE, finite inputs only)
__device__ __forceinline__ uint16_t f2bf(float f) {
  const uint32_t x = __float_as_uint(f);
  return (uint16_t)((x + 0x7FFFu + ((x >> 16) & 1u)) >> 16);
}

// split 8 consecutive floats into bf16 hi/lo short8 fragments
__device__ __forceinline__ void split8(const float4 a, const float4 b,
                                       short8_t& hi, short8_t& lo) {
  const float f[8] = {a.x, a.y, a.z, a.w, b.x, b.y, b.z, b.w};
#pragma unroll
  for (int j = 0; j < 8; ++j) {
    const uint16_t hb = f2bf(f[j]);
    const float fh = __uint_as_float((uint32_t)hb << 16);
    const uint16_t lb = f2bf(f[j] - fh);
    hi[j] = (short)hb;
    lo[j] = (short)lb;
  }
}

// ============================================================================
// Pre-kernel: split W (fp32, 1 MB) into bf16 hi/lo planes, fragment-linear.
// Same f2bf split as the main kernel -> identical numerics.
// ============================================================================
__global__ __launch_bounds__(256)
void w_split_kernel(const float* __restrict__ W) {
  const int g = blockIdx.x * 256 + threadIdx.x;  // 0..16383
#pragma unroll
  for (int r = 0; r < 2; ++r) {
    const int u = g * 2 + r;        // unit id 0..32767 (one unit = 8 k of one e)
    const int e = u >> 9;           // 512 k-octets per expert
    const int k0 = (u & 511) * 8;
    const float* wp = W + (size_t)e * D_DIM + k0;
    const float4 a = *reinterpret_cast<const float4*>(wp);
    const float4 b = *reinterpret_cast<const float4*>(wp + 4);
    short8_t hi, lo;
    split8(a, b, hi, lo);
    const int ks = k0 >> 5, q = (k0 >> 3) & 3;
    const int subE = e >> 4, ee = e & 15;
    const int idx = ks * 2048 + subE * 512 + q * 128 + ee * 8;
    *reinterpret_cast<short8_t*>(Whi_g + idx) = hi;
    *reinterpret_cast<short8_t*>(Wlo_g + idx) = lo;
  }
}

// ============================================================================
// MFMA router kernel — BARRIER-FREE main loop. 512 blocks x 256 threads
// (4 waves). Block: 16 rows x 64 e; wave w owns the 16x16 tile at experts
// w*16..+15 via mfma_f32_16x16x32_bf16 with the validated 3-product
// bf16-split (Alo*Bhi + Ahi*Blo + Ahi*Bhi, same order).
//
// ROUND 5 CHANGE: __launch_bounds__(256, 2). The grid caps residency at
// 2 blocks/CU = 2 waves/SIMD, but without the hint the compiler allocated
// only 48 VGPRs (targeting 8 waves/SIMD that can never exist) and strangled
// the software pipeline — round-4 counters: 70% idle, VALUBusy 27%,
// MfmaUtil 3.9%. With a 256-VGPR budget and unroll-8 the compiler can keep
// ~8 iterations of A+B loads in flight, hiding L2 (~200cy) and HBM (~900cy)
// latency behind issue-ahead ILP — the only latency-hiding resource at
// 2 waves/SIMD.
// ============================================================================
__global__ __launch_bounds__(256, 2)
void router_mfma_kernel(const float* __restrict__ h,
                        const float* __restrict__ bias,
                        float* __restrict__ out,
                        unsigned char* __restrict__ flags) {
  __shared__ float logits_lds[ROWS * 65];  // 4.2 KB, +1 pad

  const int tid  = threadIdx.x;
  const int wave = tid >> 6;   // n_sub: experts wave*16..+15
  const int lane = tid & 63;
  const int row0 = blockIdx.x * ROWS;

  // A fragment address: m = lane&15, k-octet = lane>>4 (k = koct*8 + j)
  const int a_row  = lane & 15;
  const int a_koct = lane >> 4;
  const float* aptr = h + (size_t)(row0 + a_row) * D_DIM + a_koct * 8;

  // B fragment base: ee = lane&15, q = lane>>4
  const int b_off = wave * 512 + (lane >> 4) * 128 + (lane & 15) * 8;
  const short* bh_base = Whi_g + b_off;
  const short* bl_base = Wlo_g + b_off;

  f32x4 acc = {0.0f, 0.0f, 0.0f, 0.0f};

#pragma unroll 8
  for (int ks = 0; ks < NKSTEP; ++ks) {
    const float4 a0 = *reinterpret_cast<const float4*>(aptr + ks * 32);
    const float4 a1 = *reinterpret_cast<const float4*>(aptr + ks * 32 + 4);
    const short8_t bh = *reinterpret_cast<const short8_t*>(bh_base + (size_t)ks * 2048);
    const short8_t bl = *reinterpret_cast<const short8_t*>(bl_base + (size_t)ks * 2048);
    short8_t ah, al;
    split8(a0, a1, ah, al);
    acc = __builtin_amdgcn_mfma_f32_16x16x32_bf16(al, bh, acc, 0, 0, 0);
    acc = __builtin_amdgcn_mfma_f32_16x16x32_bf16(ah, bl, acc, 0, 0, 0);
    acc = __builtin_amdgcn_mfma_f32_16x16x32_bf16(ah, bh, acc, 0, 0, 0);
  }

  // epilogue: C/D layout col=lane&15, row=(lane>>4)*4+reg -> logits LDS
  {
    const int q   = lane >> 4;
    const int col = wave * 16 + (lane & 15);
#pragma unroll
    for (int reg = 0; reg < 4; ++reg) {
      const int m = q * 4 + reg;
      logits_lds[m * 65 + col] = acc[reg];
    }
  }
  __syncthreads();

  // finalize: wave handles rows 4*wave..+3, lane = expert — VALIDATED path
  const int e = lane;
  const double be = (double)bias[e];
  for (int rr = 0; rr < 4; ++rr) {
    const int rloc = wave * 4 + rr;
    const int t = row0 + rloc;
    const double logit = (double)logits_lds[rloc * 65 + e] + be;

    float mask, weight;
    double gap;
    finalize_row_f64(logit, e, t, mask, weight, gap);

    const int idx = t * 64 + e;
    out[idx]          = mask;
    out[TE + idx]     = weight;
    out[2 * TE + idx] = (float)logit;
    if (e == 0) flags[t] = (gap < GAP_MARGIN) ? 1 : 0;
  }
}

// ============================================================================
// Fixup kernel — parallel-W redesign (validated round 4: out of top-5).
// One block (512 thr, 8 waves) per row, early exit when unflagged. lane =
// expert: dense contiguous float4 streams of W[e][slice], 4 interleaved f64
// chains; h row staged in LDS, uniform-address broadcast reads.
// ============================================================================
__global__ __launch_bounds__(512)
void router_fixup_kernel(const float* __restrict__ h,
                         const float* __restrict__ W,
                         const float* __restrict__ bias,
                         const unsigned char* __restrict__ flags,
                         float* __restrict__ out) {
  const int t = blockIdx.x;
  if (flags[t] == 0) return;

  __shared__ float  h_lds[D_DIM];          // 16 KB
  __shared__ double red[FIX_WAVES][64];    // 4 KB

  const int tid  = threadIdx.x;
  const int wv   = tid >> 6;
  const int lane = tid & 63;

  // stage h row, coalesced float4 (512 thr x 2 x 16B = 16 KB)
  {
    const float4* hrow4 = reinterpret_cast<const float4*>(h + (size_t)t * D_DIM);
    float4* hl4 = reinterpret_cast<float4*>(h_lds);
    hl4[tid]       = hrow4[tid];
    hl4[tid + 512] = hrow4[tid + 512];
  }
  __syncthreads();

  // lane = expert e; wave wv covers cols [wv*512, wv*512+512)
  const int e = lane;
  const float* wrow = W + (size_t)e * D_DIM + wv * FIX_COLS;
  const float* hseg = h_lds + wv * FIX_COLS;

  double acc0 = 0.0, acc1 = 0.0, acc2 = 0.0, acc3 = 0.0;
#pragma unroll 8
  for (int c = 0; c < FIX_COLS; c += 16) {
    const float4 w0 = *reinterpret_cast<const float4*>(wrow + c);
    const float4 w1 = *reinterpret_cast<const float4*>(wrow + c + 4);
    const float4 w2 = *reinterpret_cast<const float4*>(wrow + c + 8);
    const float4 w3 = *reinterpret_cast<const float4*>(wrow + c + 12);
    acc0 = fma((double)w0.x, (double)hseg[c + 0], acc0);
    acc0 = fma((double)w0.y, (double)hseg[c + 1], acc0);
    acc0 = fma((double)w0.z, (double)hseg[c + 2], acc0);
    acc0 = fma((double)w0.w, (double)hseg[c + 3], acc0);
    acc1 = fma((double)w1.x, (double)hseg[c + 4], acc1);
    acc1 = fma((double)w1.y, (double)hseg[c + 5], acc1);
    acc1 = fma((double)w1.z, (double)hseg[c + 6], acc1);
    acc1 = fma((double)w1.w, (double)hseg[c + 7], acc1);
    acc2 = fma((double)w2.x, (double)hseg[c + 8], acc2);
    acc2 = fma((double)w2.y, (double)hseg[c + 9], acc2);
    acc2 = fma((double)w2.z, (double)hseg[c + 10], acc2);
    acc2 = fma((double)w2.w, (double)hseg[c + 11], acc2);
    acc3 = fma((double)w3.x, (double)hseg[c + 12], acc3);
    acc3 = fma((double)w3.y, (double)hseg[c + 13], acc3);
    acc3 = fma((double)w3.z, (double)hseg[c + 14], acc3);
    acc3 = fma((double)w3.w, (double)hseg[c + 15], acc3);
  }
  red[wv][e] = (acc0 + acc1) + (acc2 + acc3);
  __syncthreads();

  if (wv == 0) {
    double s = red[0][e];
#pragma unroll
    for (int i = 1; i < FIX_WAVES; ++i) s += red[i][e];
    const double logit = s + (double)bias[e];

    float mask, weight;
    double gap;
    finalize_row_f64(logit, e, t, mask, weight, gap);

    const int idx = t * 64 + e;
    out[idx]          = mask;
    out[TE + idx]     = weight;
    out[2 * TE + idx] = (float)logit;
  }
}

extern "C" void kernel_launch(void* const* d_in, const int* in_sizes, int n_in,
                              void* d_out, int out_size, void* d_ws, size_t ws_size,
                              hipStream_t stream) {
  const float* h    = (const float*)d_in[0];
  const float* W    = (const float*)d_in[1];
  const float* bias = (const float*)d_in[2];
  // d_in[3] = k (always 8) — hard-coded top-8
  float* out = (float*)d_out;
  unsigned char* flags = (unsigned char*)d_ws;  // 8192 B, fully rewritten per call

  w_split_kernel<<<64, 256, 0, stream>>>(W);
  router_mfma_kernel<<<T_DIM / ROWS, 256, 0, stream>>>(h, bias, out, flags);
  router_fixup_kernel<<<T_DIM, 512, 0, stream>>>(h, W, bias, flags, out);
}

// Round 6
// 330.645 us; speedup vs baseline: 1.0879x; 1.0879x over previous
//
#include <hip/hip_runtime.h>
#include <stdint.h>
#include <math.h>

#define T_DIM 8192
#define D_DIM 4096
#define E_DIM 64
#define TE (T_DIM * E_DIM)  // 524288
#define GAP_MARGIN 2e-3     // > 2x provable worst-case bf16-split logit error (9.4e-4)
#define ROWS 16             // rows per block (mfma kernel)
#define BK 256              // k per chunk
#define NCHUNK (D_DIM / BK) // 16
#define FIX_WAVES 8
#define FIX_COLS (D_DIM / FIX_WAVES)  // 512 cols per wave

typedef __attribute__((ext_vector_type(8))) short short8_t;  // 8 bf16 (4 VGPRs)
typedef __attribute__((ext_vector_type(4))) float f32x4;

// ============================================================================
// W bf16 hi/lo planes in fragment-linear order, filled once per call by
// w_split_kernel. idx = ks*2048 + subE*512 + q*128 + ee*8 + j where
// e = subE*16+ee, k = ks*32 + q*8 + j. Per-wave B-fragment read is a fully
// coalesced 1KB global_load_dwordx4 per wave — B never touches LDS.
// ============================================================================
__device__ __align__(16) short Whi_g[E_DIM * D_DIM];  // 512 KB
__device__ __align__(16) short Wlo_g[E_DIM * D_DIM];  // 512 KB

// ============================================================================
// Threefry-2x32, key = (0, 42), 20 rounds — VALIDATED (prior session r3/4/5)
// ============================================================================
__device__ __forceinline__ void threefry2x32_k42(uint32_t x0, uint32_t x1,
                                                 uint32_t& o0, uint32_t& o1) {
  const uint32_t ks0 = 0u, ks1 = 42u;
  const uint32_t ks2 = 0x1BD11BDAu ^ ks0 ^ ks1;
  x0 += ks0; x1 += ks1;
#define TF_RND(r) { x0 += x1; x1 = (x1 << (r)) | (x1 >> (32 - (r))); x1 ^= x0; }
  TF_RND(13) TF_RND(15) TF_RND(26) TF_RND(6)   x0 += ks1; x1 += ks2 + 1u;
  TF_RND(17) TF_RND(29) TF_RND(16) TF_RND(24)  x0 += ks2; x1 += ks0 + 2u;
  TF_RND(13) TF_RND(15) TF_RND(26) TF_RND(6)   x0 += ks0; x1 += ks1 + 3u;
  TF_RND(17) TF_RND(29) TF_RND(16) TF_RND(24)  x0 += ks1; x1 += ks2 + 4u;
  TF_RND(13) TF_RND(15) TF_RND(26) TF_RND(6)   x0 += ks2; x1 += ks0 + 5u;
#undef TF_RND
  o0 = x0; o1 = x1;
}

__device__ __forceinline__ uint32_t jax_random_bits32(uint32_t j) {
  uint32_t o0, o1;
  threefry2x32_k42(0u, j, o0, o1);
  return o0 ^ o1;
}

// f64 finalize per row (lane = expert) — VALIDATED, unchanged
__device__ __forceinline__ void finalize_row_f64(double logit, int e, int t,
                                                 float& mask_out, float& weight_out,
                                                 double& gap_out) {
  double m = logit;
#pragma unroll
  for (int off = 1; off < 64; off <<= 1) {
    const double om = __shfl_xor(m, off, 64);
    m = (om > m) ? om : m;
  }
  const double pe = exp(logit - m);
  double s = pe;
#pragma unroll
  for (int off = 1; off < 64; off <<= 1) s += __shfl_xor(s, off, 64);
  weight_out = (float)(pe / s);

  const int idx = t * 64 + e;
  const uint32_t bits = jax_random_bits32((uint32_t)idx);
  const float f01 = __uint_as_float((bits >> 9) | 0x3f800000u) - 1.0f;
  const float minv = 1e-6f;
  const float maxv = 0.999999f;
  float u = __fadd_rn(__fmul_rn(f01, maxv - minv), minv);
  u = fmaxf(minv, u);
  const double g = -log(-log((double)u));
  const double sel = logit + g;

  float mask = 0.0f;
  double cur = sel;
  double v8 = 0.0, v9 = 0.0;
  for (int it = 0; it < 9; ++it) {
    double v = cur;
    int vi = e;
#pragma unroll
    for (int off = 1; off < 64; off <<= 1) {
      const double ov = __shfl_xor(v, off, 64);
      const int    oi = __shfl_xor(vi, off, 64);
      if (ov > v || (ov == v && oi < vi)) { v = ov; vi = oi; }
    }
    if (it < 8) {
      if (vi == e) { mask = 1.0f; cur = -__builtin_inf(); }
      if (it == 7) v8 = v;
    } else {
      v9 = v;
    }
  }
  mask_out = mask;
  gap_out = v8 - v9;
}

// fp32 -> bf16 (RNE, finite inputs only)
__device__ __forceinline__ uint16_t f2bf(float f) {
  const uint32_t x = __float_as_uint(f);
  return (uint16_t)((x + 0x7FFFu + ((x >> 16) & 1u)) >> 16);
}

// split 8 consecutive floats into bf16 hi/lo short8 fragments
__device__ __forceinline__ void split8(const float4 a, const float4 b,
                                       short8_t& hi, short8_t& lo) {
  const float f[8] = {a.x, a.y, a.z, a.w, b.x, b.y, b.z, b.w};
#pragma unroll
  for (int j = 0; j < 8; ++j) {
    const uint16_t hb = f2bf(f[j]);
    const float fh = __uint_as_float((uint32_t)hb << 16);
    const uint16_t lb = f2bf(f[j] - fh);
    hi[j] = (short)hb;
    lo[j] = (short)lb;
  }
}

// ============================================================================
// Pre-kernel: split W (fp32, 1 MB) into bf16 hi/lo planes, fragment-linear.
// Same f2bf split as the main kernel -> identical numerics.
// ============================================================================
__global__ __launch_bounds__(256)
void w_split_kernel(const float* __restrict__ W) {
  const int g = blockIdx.x * 256 + threadIdx.x;  // 0..16383
#pragma unroll
  for (int r = 0; r < 2; ++r) {
    const int u = g * 2 + r;        // unit id 0..32767 (one unit = 8 k of one e)
    const int e = u >> 9;           // 512 k-octets per expert
    const int k0 = (u & 511) * 8;
    const float* wp = W + (size_t)e * D_DIM + k0;
    const float4 a = *reinterpret_cast<const float4*>(wp);
    const float4 b = *reinterpret_cast<const float4*>(wp + 4);
    short8_t hi, lo;
    split8(a, b, hi, lo);
    const int ks = k0 >> 5, q = (k0 >> 3) & 3;
    const int subE = e >> 4, ee = e & 15;
    const int idx = ks * 2048 + subE * 512 + q * 128 + ee * 8;
    *reinterpret_cast<short8_t*>(Whi_g + idx) = hi;
    *reinterpret_cast<short8_t*>(Wlo_g + idx) = lo;
  }
}

// ============================================================================
// MFMA router kernel — LDS-staged A (split ONCE per block, not 4x per wave),
// double-buffered, ONE barrier per chunk, depth-2 register prefetch.
// 512 blocks x 256 threads (4 waves); block = 16 rows x 64 e; wave w owns
// experts w*16..+15 via mfma_f32_16x16x32_bf16, validated 3-product split
// (Alo*Bhi + Ahi*Blo + Ahi*Bhi, same order -> bitwise-identical logits).
//
// A staging: thread owns (row r = tid>>4, 16 consecutive k at (tid&15)*16) of
// each 256-k chunk -> 2 short8 units per plane, XOR-swizzled u^=(u>>4)&7
// (both sides; each bank-quad hit exactly 8x/wave on write AND read = HW
// minimum, conflict-free — round-1-verified layout).
// Pipeline: chunks c,c+1 preloaded in named reg-sets Ra/Rb (static indexing);
// at chunk c we write Ra->LDS, sync, issue loads for chunk c+2 into Ra, then
// run the 8-kstep MFMA phase — loads stay in flight across ~2 MFMA phases
// (~1000 cyc >= HBM latency). Safety of 1 barrier/chunk: write@c+1 (buf1) vs
// readers@c-1 (buf1) are ordered by barrier@c.
// B: direct from fragment-linear global planes (L2-resident, zero LDS/VALU).
// ============================================================================
__global__ __launch_bounds__(256)
void router_mfma_kernel(const float* __restrict__ h,
                        const float* __restrict__ bias,
                        float* __restrict__ out,
                        unsigned char* __restrict__ flags) {
  __shared__ __align__(16) short Ahi[2][ROWS * BK];  // 2 x 8 KB
  __shared__ __align__(16) short Alo[2][ROWS * BK];  // 2 x 8 KB
  __shared__ float logits_lds[ROWS * 65];            // 4.2 KB, +1 pad

  const int tid  = threadIdx.x;
  const int wave = tid >> 6;   // n_sub: experts wave*16..+15
  const int lane = tid & 63;
  const int row0 = blockIdx.x * ROWS;

  // ---- A staging geometry: thread -> (row r, k in [k0, k0+16)) of chunk
  const int r  = tid >> 4;
  const int k0 = (tid & 15) * 16;
  const int sA  = k0 >> 5;            // kstep of first unit
  const int qA  = (k0 >> 3) & 3;      // in {0, 2}
  const int u0A = sA * 64 + qA * 16 + r;
  const int u0B = u0A + 16;           // second unit: q+1
  const int uA  = u0A ^ ((u0A >> 4) & 7);   // conflict-free swizzle
  const int uB  = u0B ^ ((u0B >> 4) & 7);
  const float* hst = h + (size_t)(row0 + r) * D_DIM + k0;

  // ---- B fragment base: subE = wave, ee = lane&15, q = lane>>4
  const int b_off = wave * 512 + (lane >> 4) * 128 + (lane & 15) * 8;

  f32x4 acc = {0.0f, 0.0f, 0.0f, 0.0f};

  // depth-2 prefetch registers (named sets — static indexing only)
  float4 Ra0, Ra1, Ra2, Ra3, Rb0, Rb1, Rb2, Rb3;
  Ra0 = *reinterpret_cast<const float4*>(hst + 0);
  Ra1 = *reinterpret_cast<const float4*>(hst + 4);
  Ra2 = *reinterpret_cast<const float4*>(hst + 8);
  Ra3 = *reinterpret_cast<const float4*>(hst + 12);
  Rb0 = *reinterpret_cast<const float4*>(hst + BK + 0);
  Rb1 = *reinterpret_cast<const float4*>(hst + BK + 4);
  Rb2 = *reinterpret_cast<const float4*>(hst + BK + 8);
  Rb3 = *reinterpret_cast<const float4*>(hst + BK + 12);

#define CHUNK_STEP(R0, R1, R2, R3, BUF, CC)                                    \
  {                                                                            \
    short8_t hi_, lo_;                                                         \
    split8(R0, R1, hi_, lo_);                                                  \
    *reinterpret_cast<short8_t*>(&Ahi[BUF][uA * 8]) = hi_;                     \
    *reinterpret_cast<short8_t*>(&Alo[BUF][uA * 8]) = lo_;                     \
    split8(R2, R3, hi_, lo_);                                                  \
    *reinterpret_cast<short8_t*>(&Ahi[BUF][uB * 8]) = hi_;                     \
    *reinterpret_cast<short8_t*>(&Alo[BUF][uB * 8]) = lo_;                     \
    __syncthreads();                                                           \
    if ((CC) + 2 < NCHUNK) {                                                   \
      const float* p_ = hst + ((CC) + 2) * BK;                                 \
      R0 = *reinterpret_cast<const float4*>(p_ + 0);                           \
      R1 = *reinterpret_cast<const float4*>(p_ + 4);                           \
      R2 = *reinterpret_cast<const float4*>(p_ + 8);                           \
      R3 = *reinterpret_cast<const float4*>(p_ + 12);                          \
    }                                                                          \
    _Pragma("unroll")                                                          \
    for (int s_ = 0; s_ < BK / 32; ++s_) {                                     \
      const int ur0_ = s_ * 64 + lane;                                         \
      const int ur_  = ur0_ ^ ((ur0_ >> 4) & 7);                               \
      const short8_t ah_ = *reinterpret_cast<const short8_t*>(&Ahi[BUF][ur_ * 8]); \
      const short8_t al_ = *reinterpret_cast<const short8_t*>(&Alo[BUF][ur_ * 8]); \
      const size_t bo_ = (size_t)((CC) * (BK / 32) + s_) * 2048 + b_off;       \
      const short8_t bh_ = *reinterpret_cast<const short8_t*>(Whi_g + bo_);    \
      const short8_t bl_ = *reinterpret_cast<const short8_t*>(Wlo_g + bo_);    \
      acc = __builtin_amdgcn_mfma_f32_16x16x32_bf16(al_, bh_, acc, 0, 0, 0);   \
      acc = __builtin_amdgcn_mfma_f32_16x16x32_bf16(ah_, bl_, acc, 0, 0, 0);   \
      acc = __builtin_amdgcn_mfma_f32_16x16x32_bf16(ah_, bh_, acc, 0, 0, 0);   \
    }                                                                          \
  }

  for (int c = 0; c < NCHUNK; c += 2) {
    CHUNK_STEP(Ra0, Ra1, Ra2, Ra3, 0, c)
    CHUNK_STEP(Rb0, Rb1, Rb2, Rb3, 1, c + 1)
  }
#undef CHUNK_STEP

  // epilogue: C/D layout col=lane&15, row=(lane>>4)*4+reg -> logits LDS
  {
    const int q   = lane >> 4;
    const int col = wave * 16 + (lane & 15);
#pragma unroll
    for (int reg = 0; reg < 4; ++reg) {
      const int m = q * 4 + reg;
      logits_lds[m * 65 + col] = acc[reg];
    }
  }
  __syncthreads();

  // finalize: wave handles rows 4*wave..+3, lane = expert — VALIDATED path
  const int e = lane;
  const double be = (double)bias[e];
  for (int rr = 0; rr < 4; ++rr) {
    const int rloc = wave * 4 + rr;
    const int t = row0 + rloc;
    const double logit = (double)logits_lds[rloc * 65 + e] + be;

    float mask, weight;
    double gap;
    finalize_row_f64(logit, e, t, mask, weight, gap);

    const int idx = t * 64 + e;
    out[idx]          = mask;
    out[TE + idx]     = weight;
    out[2 * TE + idx] = (float)logit;
    if (e == 0) flags[t] = (gap < GAP_MARGIN) ? 1 : 0;
  }
}

// ============================================================================
// Fixup kernel — parallel-W redesign (validated round 4: out of top-5).
// One block (512 thr, 8 waves) per row, early exit when unflagged. lane =
// expert: dense contiguous float4 streams of W[e][slice], 4 interleaved f64
// chains; h row staged in LDS, uniform-address broadcast reads.
// ============================================================================
__global__ __launch_bounds__(512)
void router_fixup_kernel(const float* __restrict__ h,
                         const float* __restrict__ W,
                         const float* __restrict__ bias,
                         const unsigned char* __restrict__ flags,
                         float* __restrict__ out) {
  const int t = blockIdx.x;
  if (flags[t] == 0) return;

  __shared__ float  h_lds[D_DIM];          // 16 KB
  __shared__ double red[FIX_WAVES][64];    // 4 KB

  const int tid  = threadIdx.x;
  const int wv   = tid >> 6;
  const int lane = tid & 63;

  // stage h row, coalesced float4 (512 thr x 2 x 16B = 16 KB)
  {
    const float4* hrow4 = reinterpret_cast<const float4*>(h + (size_t)t * D_DIM);
    float4* hl4 = reinterpret_cast<float4*>(h_lds);
    hl4[tid]       = hrow4[tid];
    hl4[tid + 512] = hrow4[tid + 512];
  }
  __syncthreads();

  // lane = expert e; wave wv covers cols [wv*512, wv*512+512)
  const int e = lane;
  const float* wrow = W + (size_t)e * D_DIM + wv * FIX_COLS;
  const float* hseg = h_lds + wv * FIX_COLS;

  double acc0 = 0.0, acc1 = 0.0, acc2 = 0.0, acc3 = 0.0;
#pragma unroll 8
  for (int c = 0; c < FIX_COLS; c += 16) {
    const float4 w0 = *reinterpret_cast<const float4*>(wrow + c);
    const float4 w1 = *reinterpret_cast<const float4*>(wrow + c + 4);
    const float4 w2 = *reinterpret_cast<const float4*>(wrow + c + 8);
    const float4 w3 = *reinterpret_cast<const float4*>(wrow + c + 12);
    acc0 = fma((double)w0.x, (double)hseg[c + 0], acc0);
    acc0 = fma((double)w0.y, (double)hseg[c + 1], acc0);
    acc0 = fma((double)w0.z, (double)hseg[c + 2], acc0);
    acc0 = fma((double)w0.w, (double)hseg[c + 3], acc0);
    acc1 = fma((double)w1.x, (double)hseg[c + 4], acc1);
    acc1 = fma((double)w1.y, (double)hseg[c + 5], acc1);
    acc1 = fma((double)w1.z, (double)hseg[c + 6], acc1);
    acc1 = fma((double)w1.w, (double)hseg[c + 7], acc1);
    acc2 = fma((double)w2.x, (double)hseg[c + 8], acc2);
    acc2 = fma((double)w2.y, (double)hseg[c + 9], acc2);
    acc2 = fma((double)w2.z, (double)hseg[c + 10], acc2);
    acc2 = fma((double)w2.w, (double)hseg[c + 11], acc2);
    acc3 = fma((double)w3.x, (double)hseg[c + 12], acc3);
    acc3 = fma((double)w3.y, (double)hseg[c + 13], acc3);
    acc3 = fma((double)w3.z, (double)hseg[c + 14], acc3);
    acc3 = fma((double)w3.w, (double)hseg[c + 15], acc3);
  }
  red[wv][e] = (acc0 + acc1) + (acc2 + acc3);
  __syncthreads();

  if (wv == 0) {
    double s = red[0][e];
#pragma unroll
    for (int i = 1; i < FIX_WAVES; ++i) s += red[i][e];
    const double logit = s + (double)bias[e];

    float mask, weight;
    double gap;
    finalize_row_f64(logit, e, t, mask, weight, gap);

    const int idx = t * 64 + e;
    out[idx]          = mask;
    out[TE + idx]     = weight;
    out[2 * TE + idx] = (float)logit;
  }
}

extern "C" void kernel_launch(void* const* d_in, const int* in_sizes, int n_in,
                              void* d_out, int out_size, void* d_ws, size_t ws_size,
                              hipStream_t stream) {
  const float* h    = (const float*)d_in[0];
  const float* W    = (const float*)d_in[1];
  const float* bias = (const float*)d_in[2];
  // d_in[3] = k (always 8) — hard-coded top-8
  float* out = (float*)d_out;
  unsigned char* flags = (unsigned char*)d_ws;  // 8192 B, fully rewritten per call

  w_split_kernel<<<64, 256, 0, stream>>>(W);
  router_mfma_kernel<<<T_DIM / ROWS, 256, 0, stream>>>(h, bias, out, flags);
  router_fixup_kernel<<<T_DIM, 512, 0, stream>>>(h, W, bias, flags, out);
}

// Round 7
// 305.656 us; speedup vs baseline: 1.1769x; 1.0818x over previous
//
#include <hip/hip_runtime.h>
#include <stdint.h>
#include <math.h>

#define T_DIM 8192
#define D_DIM 4096
#define E_DIM 64
#define TE (T_DIM * E_DIM)  // 524288
#define GAP_MARGIN 2e-3     // > 2x provable worst-case bf16-split logit error (9.4e-4)
#define ROWS 32             // rows per block (mfma kernel)
#define BK 256              // k per chunk
#define NCHUNK (D_DIM / BK) // 16
#define FIX_WAVES 16
#define FIX_COLS (D_DIM / FIX_WAVES)  // 256 cols per wave

typedef __attribute__((ext_vector_type(8))) short short8_t;  // 8 bf16 (4 VGPRs)
typedef __attribute__((ext_vector_type(4))) float f32x4;

// Raw barrier: LDS-drain only. Does NOT drain vmcnt -> global loads (A
// prefetch regs, B fragment regs) stay in flight across chunk barriers.
// __syncthreads() would emit s_waitcnt vmcnt(0) and kill the pipeline.
// "memory" clobbers pin compiler-level ordering of the ds_write/ds_read.
#define BAR() do {                                            \
    asm volatile("s_waitcnt lgkmcnt(0)" ::: "memory");        \
    __builtin_amdgcn_s_barrier();                             \
    asm volatile("" ::: "memory");                            \
  } while (0)

// ============================================================================
// W bf16 hi/lo planes in fragment-linear order, filled once per call by
// w_split_kernel. idx = ks*2048 + subE*512 + q*128 + ee*8 + j where
// e = subE*16+ee, k = ks*32 + q*8 + j. Per-wave B-fragment read is a fully
// coalesced 1KB global_load_dwordx4 per wave — B never touches LDS.
// ============================================================================
__device__ __align__(16) short Whi_g[E_DIM * D_DIM];  // 512 KB
__device__ __align__(16) short Wlo_g[E_DIM * D_DIM];  // 512 KB

// ============================================================================
// Threefry-2x32, key = (0, 42), 20 rounds — VALIDATED (prior session r3/4/5)
// ============================================================================
__device__ __forceinline__ void threefry2x32_k42(uint32_t x0, uint32_t x1,
                                                 uint32_t& o0, uint32_t& o1) {
  const uint32_t ks0 = 0u, ks1 = 42u;
  const uint32_t ks2 = 0x1BD11BDAu ^ ks0 ^ ks1;
  x0 += ks0; x1 += ks1;
#define TF_RND(r) { x0 += x1; x1 = (x1 << (r)) | (x1 >> (32 - (r))); x1 ^= x0; }
  TF_RND(13) TF_RND(15) TF_RND(26) TF_RND(6)   x0 += ks1; x1 += ks2 + 1u;
  TF_RND(17) TF_RND(29) TF_RND(16) TF_RND(24)  x0 += ks2; x1 += ks0 + 2u;
  TF_RND(13) TF_RND(15) TF_RND(26) TF_RND(6)   x0 += ks0; x1 += ks1 + 3u;
  TF_RND(17) TF_RND(29) TF_RND(16) TF_RND(24)  x0 += ks1; x1 += ks2 + 4u;
  TF_RND(13) TF_RND(15) TF_RND(26) TF_RND(6)   x0 += ks2; x1 += ks0 + 5u;
#undef TF_RND
  o0 = x0; o1 = x1;
}

__device__ __forceinline__ uint32_t jax_random_bits32(uint32_t j) {
  uint32_t o0, o1;
  threefry2x32_k42(0u, j, o0, o1);
  return o0 ^ o1;
}

// f64 finalize per row (lane = expert) — VALIDATED, unchanged
__device__ __forceinline__ void finalize_row_f64(double logit, int e, int t,
                                                 float& mask_out, float& weight_out,
                                                 double& gap_out) {
  double m = logit;
#pragma unroll
  for (int off = 1; off < 64; off <<= 1) {
    const double om = __shfl_xor(m, off, 64);
    m = (om > m) ? om : m;
  }
  const double pe = exp(logit - m);
  double s = pe;
#pragma unroll
  for (int off = 1; off < 64; off <<= 1) s += __shfl_xor(s, off, 64);
  weight_out = (float)(pe / s);

  const int idx = t * 64 + e;
  const uint32_t bits = jax_random_bits32((uint32_t)idx);
  const float f01 = __uint_as_float((bits >> 9) | 0x3f800000u) - 1.0f;
  const float minv = 1e-6f;
  const float maxv = 0.999999f;
  float u = __fadd_rn(__fmul_rn(f01, maxv - minv), minv);
  u = fmaxf(minv, u);
  const double g = -log(-log((double)u));
  const double sel = logit + g;

  float mask = 0.0f;
  double cur = sel;
  double v8 = 0.0, v9 = 0.0;
  for (int it = 0; it < 9; ++it) {
    double v = cur;
    int vi = e;
#pragma unroll
    for (int off = 1; off < 64; off <<= 1) {
      const double ov = __shfl_xor(v, off, 64);
      const int    oi = __shfl_xor(vi, off, 64);
      if (ov > v || (ov == v && oi < vi)) { v = ov; vi = oi; }
    }
    if (it < 8) {
      if (vi == e) { mask = 1.0f; cur = -__builtin_inf(); }
      if (it == 7) v8 = v;
    } else {
      v9 = v;
    }
  }
  mask_out = mask;
  gap_out = v8 - v9;
}

// fp32 -> bf16 (RNE, finite inputs only)
__device__ __forceinline__ uint16_t f2bf(float f) {
  const uint32_t x = __float_as_uint(f);
  return (uint16_t)((x + 0x7FFFu + ((x >> 16) & 1u)) >> 16);
}

// split 8 consecutive floats into bf16 hi/lo short8 fragments
__device__ __forceinline__ void split8(const float4 a, const float4 b,
                                       short8_t& hi, short8_t& lo) {
  const float f[8] = {a.x, a.y, a.z, a.w, b.x, b.y, b.z, b.w};
#pragma unroll
  for (int j = 0; j < 8; ++j) {
    const uint16_t hb = f2bf(f[j]);
    const float fh = __uint_as_float((uint32_t)hb << 16);
    const uint16_t lb = f2bf(f[j] - fh);
    hi[j] = (short)hb;
    lo[j] = (short)lb;
  }
}

// ============================================================================
// Pre-kernel: split W (fp32, 1 MB) into bf16 hi/lo planes, fragment-linear.
// Same f2bf split as the main kernel -> identical numerics.
// ============================================================================
__global__ __launch_bounds__(256)
void w_split_kernel(const float* __restrict__ W) {
  const int g = blockIdx.x * 256 + threadIdx.x;  // 0..16383
#pragma unroll
  for (int r = 0; r < 2; ++r) {
    const int u = g * 2 + r;        // unit id 0..32767 (one unit = 8 k of one e)
    const int e = u >> 9;           // 512 k-octets per expert
    const int k0 = (u & 511) * 8;
    const float* wp = W + (size_t)e * D_DIM + k0;
    const float4 a = *reinterpret_cast<const float4*>(wp);
    const float4 b = *reinterpret_cast<const float4*>(wp + 4);
    short8_t hi, lo;
    split8(a, b, hi, lo);
    const int ks = k0 >> 5, q = (k0 >> 3) & 3;
    const int subE = e >> 4, ee = e & 15;
    const int idx = ks * 2048 + subE * 512 + q * 128 + ee * 8;
    *reinterpret_cast<short8_t*>(Whi_g + idx) = hi;
    *reinterpret_cast<short8_t*>(Wlo_g + idx) = lo;
  }
}

// ============================================================================
// MFMA router kernel. 256 blocks x 512 threads (8 waves = 2 m-subs x 4
// n-subs). Block: 32 rows x 64 e. Wave (m = wave>>2, n = wave&3) owns rows
// m*16..+15, experts n*16..+15 via mfma_f32_16x16x32_bf16, validated
// 3-product split (Alo*Bhi + Ahi*Blo + Ahi*Bhi, same order).
//
// Why ROWS=32: B traffic = (8192/ROWS) x 1MB; 16->32 halves the L2 B-stream
// (512->256 MB), the round-0..6 binder (4.1 TB/s observed = concurrency-
// limited L2 equilibrium, not BW).
// B concurrency: each wave preloads its ENTIRE chunk of B (8 ksteps x hi/lo
// = 16 named short8 regs = 16 independent dwordx4 in flight), issued before
// the split phase so split8's ~400 VALU cycles cover L2 latency.
// Barriers: raw s_barrier + lgkmcnt(0) only (BAR()) — no vmcnt drain, so
// A-prefetch (depth 2) and B loads survive across chunk boundaries.
// A staging: thread owns (row r = tid>>4, 16 k at (tid&15)*16); XOR swizzle
// u ^= (u>>5)&7 folds (s*4+q) into the bank-group bits: write AND read hit
// each bank-group exactly 8 lanes/instr = HW minimum (verified by hand).
// ============================================================================
__global__ __launch_bounds__(512, 2)
void router_mfma_kernel(const float* __restrict__ h,
                        const float* __restrict__ bias,
                        float* __restrict__ out,
                        unsigned char* __restrict__ flags) {
  __shared__ __align__(16) short Ahi[2][ROWS * BK];  // 2 x 16 KB
  __shared__ __align__(16) short Alo[2][ROWS * BK];  // 2 x 16 KB
  __shared__ float logits_lds[ROWS * 65];            // 8.3 KB, +1 pad

  const int tid  = threadIdx.x;
  const int wave = tid >> 6;
  const int lane = tid & 63;
  const int m    = wave >> 2;   // 0..1: rows m*16..+15
  const int n    = wave & 3;    // 0..3: experts n*16..+15
  const int row0 = blockIdx.x * ROWS;

  // ---- A staging geometry: thread -> (row r, k in [k0, k0+16)) of chunk
  const int r  = tid >> 4;              // 0..31
  const int k0 = (tid & 15) * 16;
  const int sW  = (tid & 15) >> 1;      // kstep of the thread's units
  const int qW  = ((tid & 15) & 1) * 2; // {0, 2}
  const int u0A = sW * 128 + qW * 32 + r;
  const int u0B = u0A + 32;             // q+1
  const int uA  = u0A ^ ((u0A >> 5) & 7);
  const int uB  = u0B ^ ((u0B >> 5) & 7);
  const float* hst = h + (size_t)(row0 + r) * D_DIM + k0;

  // ---- A fragment read base: u0 = s*128 + (lane>>4)*32 + m*16 + (lane&15)
  const int ar0 = (lane >> 4) * 32 + m * 16 + (lane & 15);

  // ---- B fragment base: ee = lane&15, q = lane>>4, expert block n
  const int b_off = n * 512 + (lane >> 4) * 128 + (lane & 15) * 8;

  f32x4 acc = {0.0f, 0.0f, 0.0f, 0.0f};

  // depth-2 A prefetch registers (named sets — static indexing only)
  float4 Ra0, Ra1, Ra2, Ra3, Rb0, Rb1, Rb2, Rb3;
  Ra0 = *reinterpret_cast<const float4*>(hst + 0);
  Ra1 = *reinterpret_cast<const float4*>(hst + 4);
  Ra2 = *reinterpret_cast<const float4*>(hst + 8);
  Ra3 = *reinterpret_cast<const float4*>(hst + 12);
  Rb0 = *reinterpret_cast<const float4*>(hst + BK + 0);
  Rb1 = *reinterpret_cast<const float4*>(hst + BK + 4);
  Rb2 = *reinterpret_cast<const float4*>(hst + BK + 8);
  Rb3 = *reinterpret_cast<const float4*>(hst + BK + 12);

#define KSTEP(S, BH, BL)                                                       \
  {                                                                            \
    const int ur0_ = (S) * 128 + ar0;                                          \
    const int ur_  = ur0_ ^ ((ur0_ >> 5) & 7);                                 \
    const short8_t ah_ = *reinterpret_cast<const short8_t*>(&Ahi[BUF_][ur_ * 8]); \
    const short8_t al_ = *reinterpret_cast<const short8_t*>(&Alo[BUF_][ur_ * 8]); \
    acc = __builtin_amdgcn_mfma_f32_16x16x32_bf16(al_, BH, acc, 0, 0, 0);      \
    acc = __builtin_amdgcn_mfma_f32_16x16x32_bf16(ah_, BL, acc, 0, 0, 0);      \
    acc = __builtin_amdgcn_mfma_f32_16x16x32_bf16(ah_, BH, acc, 0, 0, 0);      \
  }

#define CHUNK_STEP(R0, R1, R2, R3, BUF, CC)                                    \
  {                                                                            \
    const int BUF_ = (BUF);                                                    \
    /* B preload: whole chunk, 16 independent loads -> named regs */           \
    const size_t bb_ = (size_t)((CC) * 8) * 2048 + b_off;                      \
    const short8_t BH0 = *reinterpret_cast<const short8_t*>(Whi_g + bb_ + 0 * 2048); \
    const short8_t BH1 = *reinterpret_cast<const short8_t*>(Whi_g + bb_ + 1 * 2048); \
    const short8_t BH2 = *reinterpret_cast<const short8_t*>(Whi_g + bb_ + 2 * 2048); \
    const short8_t BH3 = *reinterpret_cast<const short8_t*>(Whi_g + bb_ + 3 * 2048); \
    const short8_t BH4 = *reinterpret_cast<const short8_t*>(Whi_g + bb_ + 4 * 2048); \
    const short8_t BH5 = *reinterpret_cast<const short8_t*>(Whi_g + bb_ + 5 * 2048); \
    const short8_t BH6 = *reinterpret_cast<const short8_t*>(Whi_g + bb_ + 6 * 2048); \
    const short8_t BH7 = *reinterpret_cast<const short8_t*>(Whi_g + bb_ + 7 * 2048); \
    const short8_t BL0 = *reinterpret_cast<const short8_t*>(Wlo_g + bb_ + 0 * 2048); \
    const short8_t BL1 = *reinterpret_cast<const short8_t*>(Wlo_g + bb_ + 1 * 2048); \
    const short8_t BL2 = *reinterpret_cast<const short8_t*>(Wlo_g + bb_ + 2 * 2048); \
    const short8_t BL3 = *reinterpret_cast<const short8_t*>(Wlo_g + bb_ + 3 * 2048); \
    const short8_t BL4 = *reinterpret_cast<const short8_t*>(Wlo_g + bb_ + 4 * 2048); \
    const short8_t BL5 = *reinterpret_cast<const short8_t*>(Wlo_g + bb_ + 5 * 2048); \
    const short8_t BL6 = *reinterpret_cast<const short8_t*>(Wlo_g + bb_ + 6 * 2048); \
    const short8_t BL7 = *reinterpret_cast<const short8_t*>(Wlo_g + bb_ + 7 * 2048); \
    /* split prefetched A -> swizzled LDS (covers B latency with VALU) */      \
    short8_t hi_, lo_;                                                         \
    split8(R0, R1, hi_, lo_);                                                  \
    *reinterpret_cast<short8_t*>(&Ahi[BUF_][uA * 8]) = hi_;                    \
    *reinterpret_cast<short8_t*>(&Alo[BUF_][uA * 8]) = lo_;                    \
    split8(R2, R3, hi_, lo_);                                                  \
    *reinterpret_cast<short8_t*>(&Ahi[BUF_][uB * 8]) = hi_;                    \
    *reinterpret_cast<short8_t*>(&Alo[BUF_][uB * 8]) = lo_;                    \
    BAR();                                                                     \
    /* A prefetch for chunk CC+2 — survives BAR (no vmcnt drain) */            \
    if ((CC) + 2 < NCHUNK) {                                                   \
      const float* p_ = hst + ((CC) + 2) * BK;                                 \
      R0 = *reinterpret_cast<const float4*>(p_ + 0);                           \
      R1 = *reinterpret_cast<const float4*>(p_ + 4);                           \
      R2 = *reinterpret_cast<const float4*>(p_ + 8);                           \
      R3 = *reinterpret_cast<const float4*>(p_ + 12);                          \
    }                                                                          \
    KSTEP(0, BH0, BL0) KSTEP(1, BH1, BL1) KSTEP(2, BH2, BL2)                   \
    KSTEP(3, BH3, BL3) KSTEP(4, BH4, BL4) KSTEP(5, BH5, BL5)                   \
    KSTEP(6, BH6, BL6) KSTEP(7, BH7, BL7)                                      \
  }

  for (int c = 0; c < NCHUNK; c += 2) {
    CHUNK_STEP(Ra0, Ra1, Ra2, Ra3, 0, c)
    CHUNK_STEP(Rb0, Rb1, Rb2, Rb3, 1, c + 1)
  }
#undef CHUNK_STEP
#undef KSTEP

  // epilogue: C/D layout col=lane&15, row=(lane>>4)*4+reg -> logits LDS
  {
    const int q   = lane >> 4;
    const int col = n * 16 + (lane & 15);
#pragma unroll
    for (int reg = 0; reg < 4; ++reg) {
      const int mr = m * 16 + q * 4 + reg;
      logits_lds[mr * 65 + col] = acc[reg];
    }
  }
  __syncthreads();  // full sync fine here (once)

  // finalize: wave handles rows 4*wave..+3, lane = expert — VALIDATED path
  const int e = lane;
  const double be = (double)bias[e];
  for (int rr = 0; rr < 4; ++rr) {
    const int rloc = wave * 4 + rr;
    const int t = row0 + rloc;
    const double logit = (double)logits_lds[rloc * 65 + e] + be;

    float mask, weight;
    double gap;
    finalize_row_f64(logit, e, t, mask, weight, gap);

    const int idx = t * 64 + e;
    out[idx]          = mask;
    out[TE + idx]     = weight;
    out[2 * TE + idx] = (float)logit;
    if (e == 0) flags[t] = (gap < GAP_MARGIN) ? 1 : 0;
  }
}

// ============================================================================
// Fixup kernel — parallel-W design (validated round 4/6), concurrency doubled:
// 1024 threads = 16 waves x 256-col slices. One block per row, early exit
// when unflagged. lane = expert: dense contiguous float4 streams of
// W[e][slice], 4 interleaved f64 chains; h row staged in LDS (uniform-address
// broadcast reads). Same per-expert f64 sums, same finalize.
// ============================================================================
__global__ __launch_bounds__(1024)
void router_fixup_kernel(const float* __restrict__ h,
                         const float* __restrict__ W,
                         const float* __restrict__ bias,
                         const unsigned char* __restrict__ flags,
                         float* __restrict__ out) {
  const int t = blockIdx.x;
  if (flags[t] == 0) return;

  __shared__ float  h_lds[D_DIM];          // 16 KB
  __shared__ double red[FIX_WAVES][64];    // 8 KB

  const int tid  = threadIdx.x;
  const int wv   = tid >> 6;
  const int lane = tid & 63;

  // stage h row, coalesced float4 (1024 thr x 16B = 16 KB)
  {
    const float4* hrow4 = reinterpret_cast<const float4*>(h + (size_t)t * D_DIM);
    reinterpret_cast<float4*>(h_lds)[tid] = hrow4[tid];
  }
  __syncthreads();

  // lane = expert e; wave wv covers cols [wv*256, wv*256+256)
  const int e = lane;
  const float* wrow = W + (size_t)e * D_DIM + wv * FIX_COLS;
  const float* hseg = h_lds + wv * FIX_COLS;

  double acc0 = 0.0, acc1 = 0.0, acc2 = 0.0, acc3 = 0.0;
#pragma unroll 4
  for (int c = 0; c < FIX_COLS; c += 16) {
    const float4 w0 = *reinterpret_cast<const float4*>(wrow + c);
    const float4 w1 = *reinterpret_cast<const float4*>(wrow + c + 4);
    const float4 w2 = *reinterpret_cast<const float4*>(wrow + c + 8);
    const float4 w3 = *reinterpret_cast<const float4*>(wrow + c + 12);
    acc0 = fma((double)w0.x, (double)hseg[c + 0], acc0);
    acc0 = fma((double)w0.y, (double)hseg[c + 1], acc0);
    acc0 = fma((double)w0.z, (double)hseg[c + 2], acc0);
    acc0 = fma((double)w0.w, (double)hseg[c + 3], acc0);
    acc1 = fma((double)w1.x, (double)hseg[c + 4], acc1);
    acc1 = fma((double)w1.y, (double)hseg[c + 5], acc1);
    acc1 = fma((double)w1.z, (double)hseg[c + 6], acc1);
    acc1 = fma((double)w1.w, (double)hseg[c + 7], acc1);
    acc2 = fma((double)w2.x, (double)hseg[c + 8], acc2);
    acc2 = fma((double)w2.y, (double)hseg[c + 9], acc2);
    acc2 = fma((double)w2.z, (double)hseg[c + 10], acc2);
    acc2 = fma((double)w2.w, (double)hseg[c + 11], acc2);
    acc3 = fma((double)w3.x, (double)hseg[c + 12], acc3);
    acc3 = fma((double)w3.y, (double)hseg[c + 13], acc3);
    acc3 = fma((double)w3.z, (double)hseg[c + 14], acc3);
    acc3 = fma((double)w3.w, (double)hseg[c + 15], acc3);
  }
  red[wv][e] = (acc0 + acc1) + (acc2 + acc3);
  __syncthreads();

  if (wv == 0) {
    double s = red[0][e];
#pragma unroll
    for (int i = 1; i < FIX_WAVES; ++i) s += red[i][e];
    const double logit = s + (double)bias[e];

    float mask, weight;
    double gap;
    finalize_row_f64(logit, e, t, mask, weight, gap);

    const int idx = t * 64 + e;
    out[idx]          = mask;
    out[TE + idx]     = weight;
    out[2 * TE + idx] = (float)logit;
  }
}

extern "C" void kernel_launch(void* const* d_in, const int* in_sizes, int n_in,
                              void* d_out, int out_size, void* d_ws, size_t ws_size,
                              hipStream_t stream) {
  const float* h    = (const float*)d_in[0];
  const float* W    = (const float*)d_in[1];
  const float* bias = (const float*)d_in[2];
  // d_in[3] = k (always 8) — hard-coded top-8
  float* out = (float*)d_out;
  unsigned char* flags = (unsigned char*)d_ws;  // 8192 B, fully rewritten per call

  w_split_kernel<<<64, 256, 0, stream>>>(W);
  router_mfma_kernel<<<T_DIM / ROWS, 512, 0, stream>>>(h, bias, out, flags);
  router_fixup_kernel<<<T_DIM, 1024, 0, stream>>>(h, W, bias, flags, out);
}